// Round 17
// baseline (122.945 us; speedup 1.0000x reference)
//
#include <hip/hip_runtime.h>
#include <math.h>

#define D_ 256
#define NS_ 64
#define KNB_ 8
#define SEQ_ 1024
#define B_ 4
#define MAXQ_ 1024
#define NEG_ (-10000.0f)
#define BLKNEG_ (-50000.0f)
#define ZP_ 1028           // padded LDS row stride (floats)

// packed sizes (shorts)
#define MSGP_B 262144      // 64 tiles * 8 ksteps * 64 lanes * 8
#define SCNP_B 65536       // 64 tiles * 2 ksteps * 64 lanes * 8
#define ASTEPS 12          // e'(2) | s'(2) | h'(8)

typedef short bf16x8 __attribute__((ext_vector_type(8)));
typedef float f32x4 __attribute__((ext_vector_type(4)));

__device__ __forceinline__ float waveSum(float v) {
#pragma unroll
    for (int off = 32; off; off >>= 1) v += __shfl_xor(v, off, 64);
    return v;
}

__device__ __forceinline__ float blockSum(float v, float* scr) {
    const int tid = threadIdx.x;
    const int wid = tid >> 6, lane = tid & 63;
    v = waveSum(v);
    __syncthreads();
    if (lane == 0) scr[wid] = v;
    __syncthreads();
    return scr[0] + scr[1] + scr[2] + scr[3];
}

__device__ __forceinline__ void blockSum4(float v[4], float (*scr4)[4]) {
    const int tid = threadIdx.x;
    const int wid = tid >> 6, lane = tid & 63;
#pragma unroll
    for (int off = 32; off; off >>= 1) {
#pragma unroll
        for (int q = 0; q < 4; ++q) v[q] += __shfl_xor(v[q], off, 64);
    }
    __syncthreads();
    if (lane == 0) {
#pragma unroll
        for (int q = 0; q < 4; ++q) scr4[wid][q] = v[q];
    }
    __syncthreads();
#pragma unroll
    for (int q = 0; q < 4; ++q)
        v[q] = scr4[0][q] + scr4[1][q] + scr4[2][q] + scr4[3][q];
}

// split fp32 -> bf16 hi + bf16 lo (truncation; a ~= hi + lo, err ~2^-16 rel)
__device__ __forceinline__ void cvtSplit(float a, short& h, short& l) {
    const unsigned ab = __float_as_uint(a);
    h = (short)(ab >> 16);
    const float hf = __uint_as_float(ab & 0xFFFF0000u);
    l = (short)(__float_as_uint(a - hf) >> 16);
}

// A-pack index: ((sg*12 + st)*64 + kq*16 + m16)*8 + j
__device__ __forceinline__ size_t aIdx(int sg, int st, int kq, int m16, int j) {
    return ((((size_t)sg * ASTEPS + st) << 6) + (kq << 4) + m16) * 8 + j;
}

// Fused setup: fragment-major bf16-split packing + mask detect + prep.
__global__ __launch_bounds__(256) void setup_kernel(
    const float* __restrict__ messages, const float* __restrict__ scn,
    const float* __restrict__ hidden, const float* __restrict__ gvel,
    const float* __restrict__ ctx, const float* __restrict__ ent,
    const float* __restrict__ W_probe, const float* __restrict__ W_vel,
    const float* __restrict__ W_gate, const float* __restrict__ b_gate,
    short* __restrict__ msgH, short* __restrict__ msgL,
    short* __restrict__ scnH, short* __restrict__ scnL,
    const unsigned int* __restrict__ maskW, int* __restrict__ flag,
    int* __restrict__ qMeta,
    short* __restrict__ wsAh, short* __restrict__ wsAl,
    float* __restrict__ wsProbe,
    int* __restrict__ wsMode, float* __restrict__ wsGw)
{
    const int bid = blockIdx.x;
    const int tid = threadIdx.x;

    if (bid < 256) {   // messages -> packed fragments
        const int b = bid >> 6, T = bid & 63;
        const float* src = messages + (size_t)b * SEQ_ * D_;
        short* dh = msgH + (size_t)b * MSGP_B;
        short* dl = msgL + (size_t)b * MSGP_B;
#pragma unroll
        for (int it = 0; it < 2; ++it) {
            const int g = (it << 8) + tid;         // 0..511
            const int st = g >> 6, kq = (g >> 4) & 3, m16 = g & 15;
            const int t = (T << 4) + m16;
            const int k0 = (st << 5) + (kq << 3);
            const float4 v0 = *(const float4*)(src + (size_t)t * D_ + k0);
            const float4 v1 = *(const float4*)(src + (size_t)t * D_ + k0 + 4);
            short h[8], l[8];
            cvtSplit(v0.x, h[0], l[0]); cvtSplit(v0.y, h[1], l[1]);
            cvtSplit(v0.z, h[2], l[2]); cvtSplit(v0.w, h[3], l[3]);
            cvtSplit(v1.x, h[4], l[4]); cvtSplit(v1.y, h[5], l[5]);
            cvtSplit(v1.z, h[6], l[6]); cvtSplit(v1.w, h[7], l[7]);
            const size_t o = (((size_t)T * 8 + st) << 9) + (size_t)((kq << 4) + m16) * 8;
            *(short4*)(dh + o) = make_short4(h[0], h[1], h[2], h[3]);
            *(short4*)(dh + o + 4) = make_short4(h[4], h[5], h[6], h[7]);
            *(short4*)(dl + o) = make_short4(l[0], l[1], l[2], l[3]);
            *(short4*)(dl + o + 4) = make_short4(l[4], l[5], l[6], l[7]);
        }
        return;
    }

    if (bid < 320) {   // scn -> packed fragments, 4 tiles per block
        const int i = bid - 256;
        const int b = i >> 4;
        const float* src = scn + (size_t)b * SEQ_ * NS_;
        short* dh = scnH + (size_t)b * SCNP_B;
        short* dl = scnL + (size_t)b * SCNP_B;
#pragma unroll
        for (int tt = 0; tt < 4; ++tt) {
            const int T = ((i & 15) << 2) + tt;
            if (tid < 128) {
                const int st = tid >> 6, kq = (tid >> 4) & 3, m16 = tid & 15;
                const int t = (T << 4) + m16;
                const int k0 = (st << 5) + (kq << 3);
                const float4 v0 = *(const float4*)(src + (size_t)t * NS_ + k0);
                const float4 v1 = *(const float4*)(src + (size_t)t * NS_ + k0 + 4);
                short h[8], l[8];
                cvtSplit(v0.x, h[0], l[0]); cvtSplit(v0.y, h[1], l[1]);
                cvtSplit(v0.z, h[2], l[2]); cvtSplit(v0.w, h[3], l[3]);
                cvtSplit(v1.x, h[4], l[4]); cvtSplit(v1.y, h[5], l[5]);
                cvtSplit(v1.z, h[6], l[6]); cvtSplit(v1.w, h[7], l[7]);
                const size_t o = (((size_t)T * 2 + st) << 9) + (size_t)((kq << 4) + m16) * 8;
                *(short4*)(dh + o) = make_short4(h[0], h[1], h[2], h[3]);
                *(short4*)(dh + o + 4) = make_short4(h[4], h[5], h[6], h[7]);
                *(short4*)(dl + o) = make_short4(l[0], l[1], l[2], l[3]);
                *(short4*)(dl + o + 4) = make_short4(l[4], l[5], l[6], l[7]);
            }
        }
        return;
    }

    if (bid == 320) {
        __shared__ int notI, notF;
        if (tid == 0) { notI = 0; notF = 0; qMeta[0] = 0; qMeta[1] = 0; }
        __syncthreads();
        int ni = 0, nf = 0;
        for (int i = tid; i < 1024; i += 256) {
            const unsigned int w = maskW[i];
            if (w != 0u && w != 1u) ni = 1;
            if (w != 0u && w != 0x3f800000u) nf = 1;
        }
        if (ni) atomicOr(&notI, 1);
        if (nf) atomicOr(&notF, 1);
        __syncthreads();
        if (tid == 0) *flag = (!notI) ? 0 : ((!notF) ? 2 : 1);
        return;
    }

    // ---- prep: 8 rows per block; A written in fragment-major pack ----
    __shared__ float scr4[4][4];
    const int rowBase = (bid - 321) << 3;
    const int wid = tid >> 6, lane = tid & 63;
    const float* h0 = hidden + (size_t)rowBase * D_;

    float vh[8] = {};
    for (int e = 0; e < NS_; e += 4) {
        const float4 wv4 = *(const float4*)(W_vel + (size_t)tid * NS_ + e);  // thread-own row
#pragma unroll
        for (int r = 0; r < 8; ++r) {
            const float4 g4 = *(const float4*)(gvel + (size_t)(rowBase + r) * NS_ + e); // uniform
            vh[r] = fmaf(g4.x, wv4.x, fmaf(g4.y, wv4.y, fmaf(g4.z, wv4.z, fmaf(g4.w, wv4.w, vh[r]))));
        }
    }
    float pr[8] = {};
    for (int e = 0; e < D_; e += 4) {
        const float4 wp4 = *(const float4*)(W_probe + (size_t)tid * D_ + e);  // thread-own row
#pragma unroll
        for (int r = 0; r < 8; ++r) {
            const float4 h4 = *(const float4*)(h0 + (size_t)r * D_ + e);      // uniform
            pr[r] = fmaf(h4.x, wp4.x, fmaf(h4.y, wp4.y, fmaf(h4.z, wp4.z, fmaf(h4.w, wp4.w, pr[r]))));
        }
    }

    // per-wave: wave w handles rows 2w, 2w+1 (endpoint e', s', argmax, gate)
#pragma unroll
    for (int rr = 0; rr < 2; ++rr) {
        const int r = (wid << 1) + rr, row = rowBase + r;
        const int sg = row >> 4, m16 = row & 15;
        const float sv = scn[(size_t)row * NS_ + lane];
        const float gv = gvel[(size_t)row * NS_ + lane];
        const float Hn = ent[row] / 10.373491191781864f;   // log(32000)+1e-8
        const float e = sv + 0.4f * gv;
        const float ss = waveSum(e * e);
        const int stE = lane >> 5, kqE = (lane & 31) >> 3, jE = lane & 7;
        short hh, ll;
        cvtSplit((e / fmaxf(sqrtf(ss), 1e-12f)) * 5.0f * Hn, hh, ll);
        wsAh[aIdx(sg, stE, kqE, m16, jE)] = hh;
        wsAl[aIdx(sg, stE, kqE, m16, jE)] = ll;
        cvtSplit(5.0f * sv, hh, ll);
        wsAh[aIdx(sg, 2 + stE, kqE, m16, jE)] = hh;
        wsAl[aIdx(sg, 2 + stE, kqE, m16, jE)] = ll;
        float v = sv; int idx = lane;
#pragma unroll
        for (int off = 1; off < 64; off <<= 1) {
            const float ov = __shfl_xor(v, off, 64);
            const int   oi = __shfl_xor(idx, off, 64);
            if (ov > v || (ov == v && oi < idx)) { v = ov; idx = oi; }
        }
        float gd = 0.f;
#pragma unroll
        for (int j = 0; j < 4; ++j) {
            const int d = lane + (j << 6);
            gd = fmaf(h0[(size_t)r * D_ + d], W_gate[d], gd);
        }
        gd = waveSum(gd);
        if (lane == 0) {
            wsMode[row] = idx;
            const float raw = 1.f / (1.f + expf(-(gd + b_gate[0])));
            wsGw[row] = raw * ctx[row];
        }
    }

    // block-wide norms; h' written packed
    const int stH = 4 + (tid >> 5), kqH = (tid & 31) >> 3, jH = tid & 7;
#pragma unroll
    for (int g = 0; g < 2; ++g) {
        float ha4[4], va[4], vp[4];
#pragma unroll
        for (int q = 0; q < 4; ++q) {
            const int r = (g << 2) + q;
            ha4[q] = h0[(size_t)r * D_ + tid] + 0.3f * vh[r];
            va[q] = ha4[q] * ha4[q];
            vp[q] = pr[(g << 2) + q] * pr[(g << 2) + q];
        }
        blockSum4(va, scr4);
        blockSum4(vp, scr4);
#pragma unroll
        for (int q = 0; q < 4; ++q) {
            const int r = (g << 2) + q;
            const int row = rowBase + r;
            const int sg = row >> 4, m16 = row & 15;
            short hh, ll;
            cvtSplit((ha4[q] / fmaxf(sqrtf(va[q]), 1e-12f)) * 2.5f, hh, ll);
            wsAh[aIdx(sg, stH, kqH, m16, jH)] = hh;
            wsAl[aIdx(sg, stH, kqH, m16, jH)] = ll;
            wsProbe[(size_t)row * D_ + tid] = pr[r] / fmaxf(sqrtf(vp[q]), 1e-12f);
        }
    }
}

// FUSED kernel: sims (MFMA, z -> LDS) + per-row routing.  256 blocks =
// b(4) x rowgroup16(64); 512 thr = 8 waves.  Phase 1: wave w computes
// col-tiles [8w,8w+8) for all 16 rows (split-bf16 3-pass MFMA), writes
// zg/zl to padded LDS.  Barrier.  Phase 2: wave w routes rows w and w+8.
__global__ __launch_bounds__(512) void fused_kernel(
    const short* __restrict__ msgH, const short* __restrict__ msgL,
    const short* __restrict__ scnH, const short* __restrict__ scnL,
    const short* __restrict__ wsAh, const short* __restrict__ wsAl,
    const int* __restrict__ wsMode,
    const void* __restrict__ maskP,
    const int* __restrict__ maskFlag,
    const float* __restrict__ messages,
    const float* __restrict__ scn,
    const int* __restrict__ x_ids,
    const int* __restrict__ static_nb,
    const float* __restrict__ W_e1,
    const float* __restrict__ b_e1,
    const float* __restrict__ W_e2,
    const float* __restrict__ b_e2,
    const float* __restrict__ wsProbe,
    const float* __restrict__ wsGw,
    float* __restrict__ wq,          // [MAXQ][1024] dense weights
    int* __restrict__ qRows,
    int* __restrict__ qMeta,
    float* __restrict__ out)
{
    __shared__ float zgS[16 * ZP_];      // 64.3 KB
    __shared__ float zlS[16 * ZP_];      // 64.3 KB
    __shared__ uint2 lst[8][256];        // 16 KB
    __shared__ float ewLds[8][8];
    __shared__ int   mlist[8][64];

    const int bid = blockIdx.x;          // 256 blocks
    const int b = bid >> 6;
    const int sg = bid & 63;
    const int sBase = sg << 4;
    const int rowBase = (b << 10) + sBase;
    const int tid = threadIdx.x;
    const int w = tid >> 6, l = tid & 63;
    const int m16 = l & 15, kq = l >> 4;
    const int l8 = l << 3;

    // ================= phase 1: MFMA sims -> LDS =================
    {
        const int sgA = (b << 6) + sg;
        const short* AhB = wsAh + (size_t)sgA * (ASTEPS * 512) + l8;
        const short* AlB = wsAl + (size_t)sgA * (ASTEPS * 512) + l8;

        f32x4 accG[8], accL[8];
#pragma unroll
        for (int ct = 0; ct < 8; ++ct) {
            accG[ct] = (f32x4){0.f, 0.f, 0.f, 0.f};
            accL[ct] = (f32x4){0.f, 0.f, 0.f, 0.f};
        }
#pragma unroll
        for (int st = 0; st < 2; ++st) {
            const bf16x8 aeh = *(const bf16x8*)(AhB + (st << 9));
            const bf16x8 ael = *(const bf16x8*)(AlB + (st << 9));
            const bf16x8 ash = *(const bf16x8*)(AhB + ((2 + st) << 9));
            const bf16x8 asl = *(const bf16x8*)(AlB + ((2 + st) << 9));
#pragma unroll
            for (int ct = 0; ct < 8; ++ct) {
                const int mtile = (w << 3) + ct;
                const size_t bo = (size_t)b * SCNP_B + (((size_t)mtile * 2 + st) << 9) + l8;
                const bf16x8 bh = *(const bf16x8*)(scnH + bo);
                const bf16x8 bl = *(const bf16x8*)(scnL + bo);
                accG[ct] = __builtin_amdgcn_mfma_f32_16x16x32_bf16(aeh, bh, accG[ct], 0, 0, 0);
                accG[ct] = __builtin_amdgcn_mfma_f32_16x16x32_bf16(aeh, bl, accG[ct], 0, 0, 0);
                accG[ct] = __builtin_amdgcn_mfma_f32_16x16x32_bf16(ael, bh, accG[ct], 0, 0, 0);
                accL[ct] = __builtin_amdgcn_mfma_f32_16x16x32_bf16(ash, bh, accL[ct], 0, 0, 0);
                accL[ct] = __builtin_amdgcn_mfma_f32_16x16x32_bf16(ash, bl, accL[ct], 0, 0, 0);
                accL[ct] = __builtin_amdgcn_mfma_f32_16x16x32_bf16(asl, bh, accL[ct], 0, 0, 0);
            }
        }
#pragma unroll
        for (int st = 0; st < 8; ++st) {
            const bf16x8 ah = *(const bf16x8*)(AhB + ((4 + st) << 9));
            const bf16x8 al = *(const bf16x8*)(AlB + ((4 + st) << 9));
#pragma unroll
            for (int ct = 0; ct < 8; ++ct) {
                const int mtile = (w << 3) + ct;
                const size_t bo = (size_t)b * MSGP_B + (((size_t)mtile * 8 + st) << 9) + l8;
                const bf16x8 bh = *(const bf16x8*)(msgH + bo);
                const bf16x8 bl = *(const bf16x8*)(msgL + bo);
                accG[ct] = __builtin_amdgcn_mfma_f32_16x16x32_bf16(ah, bh, accG[ct], 0, 0, 0);
                accG[ct] = __builtin_amdgcn_mfma_f32_16x16x32_bf16(ah, bl, accG[ct], 0, 0, 0);
                accG[ct] = __builtin_amdgcn_mfma_f32_16x16x32_bf16(al, bh, accG[ct], 0, 0, 0);
            }
        }

        // tail: mask + mode; z -> LDS
        const int mf = *maskFlag;
        const int4 mS4 = *(const int4*)(wsMode + rowBase + (kq << 2));
        const int mSq[4] = {mS4.x, mS4.y, mS4.z, mS4.w};
#pragma unroll
        for (int ct = 0; ct < 8; ++ct) {
            const int t = (w << 7) + (ct << 4) + m16;
            const int mdt = wsMode[(b << 10) + t];
#pragma unroll
            for (int q = 0; q < 4; ++q) {
                const int r = (kq << 2) + q;
                const int s_r = sBase + r;
                const size_t mb = (size_t)s_r * SEQ_ + t;
                int blk;
                if (mf == 1)      blk = ((const unsigned char*)maskP)[mb] != 0;
                else if (mf == 2) blk = ((const float*)maskP)[mb] != 0.f;
                else              blk = ((const int*)maskP)[mb] != 0;
                if (s_r == t) blk = 1;
                zgS[r * ZP_ + t] = blk ? NEG_ : accG[ct][q];
                const int sm = (!blk) && (mdt == mSq[q]);
                zlS[r * ZP_ + t] = blk ? BLKNEG_ : (sm ? accL[ct][q] : 0.0f);
            }
        }
    }
    __syncthreads();

    // ================= phase 2: per-row routing (wave w: rows w, w+8) =====
    const float* msgB = messages + (size_t)b * SEQ_ * D_;
    const float* scnB = scn + (size_t)b * SEQ_ * NS_;
    const unsigned long long ltmask = (1ull << l) - 1ull;
    const int d4 = l << 2;

    for (int rr = 0; rr < 2; ++rr) {
        const int r = w + (rr << 3);
        const int s_r = sBase + r;
        const int row = rowBase + r;

        float zrG[16], zrL[16];
#pragma unroll
        for (int j = 0; j < 16; ++j) {
            zrG[j] = zgS[r * ZP_ + (j << 6) + l];
            zrL[j] = zlS[r * ZP_ + (j << 6) + l];
        }

        // ----- static neighbor-vocab scan -----
        const int q = x_ids[row];
        int nb[KNB_];
#pragma unroll
        for (int k = 0; k < KNB_; ++k) nb[k] = static_nb[(size_t)q * KNB_ + k];
        const float ss_l = scnB[(size_t)s_r * NS_ + l];
        float simk[KNB_] = {};
        unsigned matchedMask = 0;
        int mcW = 0;
        const int* xb = x_ids + (b << 10);
        for (int pb = 0; pb <= s_r; pb += 64) {
            const int p = pb + l;
            const int id = (p <= s_r) ? xb[p] : -2147483647;
            unsigned kmask = 0;
#pragma unroll
            for (int k = 0; k < KNB_; ++k) kmask |= (id == nb[k]) ? (1u << k) : 0u;
            unsigned long long mb = __ballot(kmask != 0u);
            while (mb) {
                const int src = __ffsll(mb) - 1; mb &= mb - 1;
                const unsigned kms = (unsigned)__shfl((int)kmask, src, 64);
                const int pp = pb + src;
                float pv = scnB[(size_t)pp * NS_ + l] * ss_l;
                pv = waveSum(pv);
                matchedMask |= kms;
#pragma unroll
                for (int k = 0; k < KNB_; ++k) {
                    if ((kms >> k) & 1u) {
                        simk[k] += pv;
                        if (mcW < 64) { if (l == 0) mlist[w][mcW] = (pp << 3) | k; ++mcW; }
                    }
                }
            }
        }
        const int kk = l >> 3, jjn = l & 7;
        float sv = simk[0];
#pragma unroll
        for (int k = 1; k < KNB_; ++k) sv = (kk == k) ? simk[k] : sv;
        const float xx = sv * W_e1[jjn] + b_e1[jjn];
        float eo = 0.5f * xx * (1.f + erff(xx * 0.70710678118654752f)) * W_e2[jjn];
        eo += __shfl_xor(eo, 1, 64); eo += __shfl_xor(eo, 2, 64); eo += __shfl_xor(eo, 4, 64);
        eo += b_e2[0];
        float m2 = eo;
        m2 = fmaxf(m2, __shfl_xor(m2, 8, 64));
        m2 = fmaxf(m2, __shfl_xor(m2, 16, 64));
        m2 = fmaxf(m2, __shfl_xor(m2, 32, 64));
        const float exv = expf(eo - m2);
        float smv = exv;
        smv += __shfl_xor(smv, 8, 64); smv += __shfl_xor(smv, 16, 64); smv += __shfl_xor(smv, 32, 64);
        if ((l & 7) == 0) ewLds[w][kk] = exv / smv;

        const float cov = (float)__popc(matchedMask) * 0.125f;
        const float gw = wsGw[row];
        const float coefG = gw;
        const float coefL = (1.f - gw) * (1.f - cov);
        const float coefS = (1.f - gw) * cov;

        // ----- local hasNb from raw zl -----
        int fl = 0;
#pragma unroll
        for (int j = 0; j < 16; ++j) fl |= (zrL[j] != 0.0f && zrL[j] > -40000.f);
        const int hasNb = __any(fl);
        if (!hasNb) {
#pragma unroll
            for (int j = 0; j < 16; ++j) {
                const int t = (j << 6) + l;
                zrL[j] = (zrL[j] <= -40000.f) ? BLKNEG_ : -0.05f * fabsf((float)(s_r - t));
            }
        }

        // ----- joint sparsemax tau -----
        float mxG = zrG[0], mxL = zrL[0];
#pragma unroll
        for (int j = 1; j < 16; ++j) { mxG = fmaxf(mxG, zrG[j]); mxL = fmaxf(mxL, zrL[j]); }
#pragma unroll
        for (int off = 32; off; off >>= 1) {
            mxG = fmaxf(mxG, __shfl_xor(mxG, off, 64));
            mxL = fmaxf(mxL, __shfl_xor(mxL, off, 64));
        }
        float tauG = mxG - 1.f, tauL = mxL - 1.f;
        for (int it = 0; it < 32; ++it) {
            float sG = 0.f, cG = 0.f, sL = 0.f, cL = 0.f;
#pragma unroll
            for (int j = 0; j < 16; ++j) {
                if (zrG[j] > tauG) { sG += zrG[j]; cG += 1.f; }
                if (zrL[j] > tauL) { sL += zrL[j]; cL += 1.f; }
            }
#pragma unroll
            for (int off = 32; off; off >>= 1) {
                sG += __shfl_xor(sG, off, 64); cG += __shfl_xor(cG, off, 64);
                sL += __shfl_xor(sL, off, 64); cL += __shfl_xor(cL, off, 64);
            }
            const float nG = (sG - 1.f) / fmaxf(cG, 1.f);
            const float nL = (sL - 1.f) / fmaxf(cL, 1.f);
            if (nG == tauG && nL == tauL) break;
            tauG = nG; tauL = nL;
        }

        int supG = 0, supL = 0;
#pragma unroll
        for (int j = 0; j < 16; ++j) {
            supG += __popcll(__ballot(zrG[j] > tauG));
            supL += __popcll(__ballot(zrL[j] > tauL));
        }
        const bool gDense = supG > 96;
        const bool lDense = supL > 96;

        int cnt = 0;
        if (!gDense) {
#pragma unroll
            for (int j = 0; j < 16; ++j) {
                const float wv = zrG[j] - tauG;
                const bool take = wv > 0.f;
                const unsigned long long m = __ballot(take);
                if (take) {
                    const int pos = cnt + __popcll(m & ltmask);
                    lst[w][pos] = make_uint2((unsigned)((j << 6) + l),
                                             __float_as_uint(coefG * wv));
                }
                cnt += __popcll(m);
            }
        }
        if (!lDense) {
#pragma unroll
            for (int j = 0; j < 16; ++j) {
                const float wv = zrL[j] - tauL;
                const bool take = wv > 0.f;
                const unsigned long long m = __ballot(take);
                if (take) {
                    const int pos = cnt + __popcll(m & ltmask);
                    lst[w][pos] = make_uint2((unsigned)((j << 6) + l),
                                             __float_as_uint(coefL * wv));
                }
                cnt += __popcll(m);
            }
        }
        const int nm = (mcW < 64) ? mcW : 64;
        for (int i = l; i < nm; i += 64) {
            const int ee = mlist[w][i];
            lst[w][cnt + i] = make_uint2((unsigned)(ee >> 3),
                                         __float_as_uint(coefS * ewLds[w][ee & 7]));
        }
        cnt += nm;

        float ox = 0.f, oy = 0.f, oz2 = 0.f, ow = 0.f;
        int i = 0;
        for (; i + 4 <= cnt; i += 4) {
            const uint2 e0 = lst[w][i + 0];
            const uint2 e1 = lst[w][i + 1];
            const uint2 e2 = lst[w][i + 2];
            const uint2 e3 = lst[w][i + 3];
            const float4 m0 = *(const float4*)(msgB + (size_t)e0.x * D_ + d4);
            const float4 m1 = *(const float4*)(msgB + (size_t)e1.x * D_ + d4);
            const float4 m2b = *(const float4*)(msgB + (size_t)e2.x * D_ + d4);
            const float4 m3 = *(const float4*)(msgB + (size_t)e3.x * D_ + d4);
            const float w0 = __uint_as_float(e0.y), w1 = __uint_as_float(e1.y);
            const float w2 = __uint_as_float(e2.y), w3 = __uint_as_float(e3.y);
            ox = fmaf(w0, m0.x, fmaf(w1, m1.x, fmaf(w2, m2b.x, fmaf(w3, m3.x, ox))));
            oy = fmaf(w0, m0.y, fmaf(w1, m1.y, fmaf(w2, m2b.y, fmaf(w3, m3.y, oy))));
            oz2 = fmaf(w0, m0.z, fmaf(w1, m1.z, fmaf(w2, m2b.z, fmaf(w3, m3.z, oz2))));
            ow = fmaf(w0, m0.w, fmaf(w1, m1.w, fmaf(w2, m2b.w, fmaf(w3, m3.w, ow))));
        }
        for (; i < cnt; ++i) {
            const uint2 e0 = lst[w][i];
            const float w0 = __uint_as_float(e0.y);
            const float4 m0 = *(const float4*)(msgB + (size_t)e0.x * D_ + d4);
            ox = fmaf(w0, m0.x, ox); oy = fmaf(w0, m0.y, oy);
            oz2 = fmaf(w0, m0.z, oz2); ow = fmaf(w0, m0.w, ow);
        }

        int slot = -1;
        if (gDense || lDense) {
            int s0 = 0;
            if (l == 0) s0 = atomicAdd(&qMeta[0], 1);
            slot = __shfl(s0, 0, 64);
        }
        if (slot >= 0 && slot < MAXQ_) {
#pragma unroll
            for (int j = 0; j < 16; ++j) {
                float wv = 0.f;
                if (gDense) wv += coefG * fmaxf(zrG[j] - tauG, 0.f);
                if (lDense) wv += coefL * fmaxf(zrL[j] - tauL, 0.f);
                wq[(size_t)slot * SEQ_ + (j << 6) + l] = wv;
            }
            if (l == 0) qRows[slot] = row;
            *(float4*)(out + (size_t)row * D_ + d4) = make_float4(ox, oy, oz2, ow);
            continue;   // this row deferred to cleanup
        }
        if (slot >= MAXQ_) {
#pragma unroll
            for (int j = 0; j < 16; ++j) {
                float wv = 0.f;
                if (gDense) wv += coefG * fmaxf(zrG[j] - tauG, 0.f);
                if (lDense) wv += coefL * fmaxf(zrL[j] - tauL, 0.f);
                unsigned long long m = __ballot(wv > 0.f);
                while (m) {
                    const int s0 = __ffsll(m) - 1; m &= m - 1;
                    const float w0 = __shfl(wv, s0, 64);
                    const float4 m4 = *(const float4*)(msgB + (size_t)((j << 6) + s0) * D_ + d4);
                    ox = fmaf(w0, m4.x, ox); oy = fmaf(w0, m4.y, oy);
                    oz2 = fmaf(w0, m4.z, oz2); ow = fmaf(w0, m4.w, ow);
                }
            }
        }

        float ssq = ox * ox + oy * oy + oz2 * oz2 + ow * ow;
        ssq = waveSum(ssq);
        const float nrm = fmaxf(sqrtf(ssq), 1e-12f);
        const float4 pr = *(const float4*)(wsProbe + (size_t)row * D_ + d4);
        float dp = (ox * pr.x + oy * pr.y + oz2 * pr.z + ow * pr.w) / nrm;
        dp = waveSum(dp);
        const float rel = 1.f / (1.f + expf(-dp));
        *(float4*)(out + (size_t)row * D_ + d4) =
            make_float4(ox * rel, oy * rel, oz2 * rel, ow * rel);
    }
}

// Kernel C: drain dense-row queue.
__global__ __launch_bounds__(256) void cleanup_kernel(
    const float* __restrict__ messages,
    const float* __restrict__ wsProbe,
    const float* __restrict__ wq,
    const int* __restrict__ qRows,
    int* __restrict__ qMeta,
    float* __restrict__ out)
{
    __shared__ float wsh[SEQ_];
    __shared__ float scr[4];
    __shared__ int idxSh;
    const int tid = threadIdx.x;
    const int nq = (qMeta[0] < MAXQ_) ? qMeta[0] : MAXQ_;
    for (;;) {
        __syncthreads();
        if (tid == 0) idxSh = atomicAdd(&qMeta[1], 1);
        __syncthreads();
        const int idx = idxSh;
        if (idx >= nq) break;
        const int row = qRows[idx];
        const int b = row >> 10;
        const float* msgB = messages + (size_t)b * SEQ_ * D_;
        for (int i = tid; i < SEQ_; i += 256)
            wsh[i] = wq[(size_t)idx * SEQ_ + i];
        __syncthreads();
        float acc = out[(size_t)row * D_ + tid];
        for (int t = 0; t < SEQ_; t += 4) {
            acc = fmaf(wsh[t + 0], msgB[(size_t)(t + 0) * D_ + tid],
                  fmaf(wsh[t + 1], msgB[(size_t)(t + 1) * D_ + tid],
                  fmaf(wsh[t + 2], msgB[(size_t)(t + 2) * D_ + tid],
                  fmaf(wsh[t + 3], msgB[(size_t)(t + 3) * D_ + tid], acc))));
        }
        const float ssq = blockSum(acc * acc, scr);
        const float nrm = fmaxf(sqrtf(ssq), 1e-12f);
        const float dp = blockSum((acc / nrm) * wsProbe[(size_t)row * D_ + tid], scr);
        const float rel = 1.f / (1.f + expf(-dp));
        out[(size_t)row * D_ + tid] = acc * rel;
    }
}

extern "C" void kernel_launch(void* const* d_in, const int* in_sizes, int n_in,
                              void* d_out, int out_size, void* d_ws, size_t ws_size,
                              hipStream_t stream) {
    const float* messages  = (const float*)d_in[0];
    const float* hidden    = (const float*)d_in[1];
    const int*   x_ids     = (const int*)d_in[2];
    const float* scn       = (const float*)d_in[3];
    const void*  mask      = d_in[4];
    const int*   static_nb = (const int*)d_in[5];
    const float* gvel      = (const float*)d_in[6];
    const float* ctx       = (const float*)d_in[7];
    const float* ent       = (const float*)d_in[8];
    const float* W_vel     = (const float*)d_in[9];
    const float* W_e1      = (const float*)d_in[10];
    const float* b_e1      = (const float*)d_in[11];
    const float* W_e2      = (const float*)d_in[12];
    const float* b_e2      = (const float*)d_in[13];
    const float* W_probe   = (const float*)d_in[14];
    const float* W_gate    = (const float*)d_in[15];
    const float* b_gate    = (const float*)d_in[16];
    float* out = (float*)d_out;
    (void)in_sizes; (void)n_in; (void)out_size; (void)ws_size;

    char* ws = (char*)d_ws;
    size_t o = 0;
    int* flag      = (int*)(ws + o);   o += 256;
    short* wsAh    = (short*)(ws + o); o += (size_t)B_ * SEQ_ * 384 * 2;   // 3.1 MB packed
    short* wsAl    = (short*)(ws + o); o += (size_t)B_ * SEQ_ * 384 * 2;
    float* wsProbe = (float*)(ws + o); o += (size_t)B_ * SEQ_ * D_ * 4;
    int* wsMode    = (int*)(ws + o);   o += (size_t)B_ * SEQ_ * 4;
    float* wsGw    = (float*)(ws + o); o += (size_t)B_ * SEQ_ * 4;
    short* msgH    = (short*)(ws + o); o += (size_t)B_ * MSGP_B * 2;       // 2 MB packed
    short* msgL    = (short*)(ws + o); o += (size_t)B_ * MSGP_B * 2;
    short* scnH    = (short*)(ws + o); o += (size_t)B_ * SCNP_B * 2;
    short* scnL    = (short*)(ws + o); o += (size_t)B_ * SCNP_B * 2;
    float* wq      = (float*)(ws + o); o += (size_t)MAXQ_ * SEQ_ * 4;      // 4 MB own buffer
    int* qMeta     = (int*)(ws + o);   o += 256;
    int* qRows     = (int*)(ws + o);   o += (size_t)MAXQ_ * 4;

    setup_kernel<<<dim3(833), dim3(256), 0, stream>>>(
        messages, scn, hidden, gvel, ctx, ent, W_probe, W_vel, W_gate, b_gate,
        msgH, msgL, scnH, scnL, (const unsigned int*)mask, flag, qMeta,
        wsAh, wsAl, wsProbe, wsMode, wsGw);
    fused_kernel<<<dim3(256), dim3(512), 0, stream>>>(
        msgH, msgL, scnH, scnL, wsAh, wsAl, wsMode, mask, flag,
        messages, scn, x_ids, static_nb, W_e1, b_e1, W_e2, b_e2,
        wsProbe, wsGw, wq, qRows, qMeta, out);
    cleanup_kernel<<<dim3(64), dim3(256), 0, stream>>>(
        messages, wsProbe, wq, qRows, qMeta, out);
}

// Round 18
// 106.754 us; speedup vs baseline: 1.1517x; 1.1517x over previous
//
#include <hip/hip_runtime.h>
#include <math.h>

#define D_ 256
#define NS_ 64
#define KNB_ 8
#define SEQ_ 1024
#define B_ 4
#define MAXQ_ 1024
#define NEG_ (-10000.0f)
#define BLKNEG_ (-50000.0f)

// packed sizes (shorts)
#define MSGP_B 262144      // 64 tiles * 8 ksteps * 64 lanes * 8
#define SCNP_B 65536       // 64 tiles * 2 ksteps * 64 lanes * 8
#define ASTEPS 12          // e'(2) | s'(2) | h'(8)

typedef short bf16x8 __attribute__((ext_vector_type(8)));
typedef float f32x4 __attribute__((ext_vector_type(4)));

__device__ __forceinline__ float waveSum(float v) {
#pragma unroll
    for (int off = 32; off; off >>= 1) v += __shfl_xor(v, off, 64);
    return v;
}

__device__ __forceinline__ float blockSum(float v, float* scr) {
    const int tid = threadIdx.x;
    const int wid = tid >> 6, lane = tid & 63;
    v = waveSum(v);
    __syncthreads();
    if (lane == 0) scr[wid] = v;
    __syncthreads();
    return scr[0] + scr[1] + scr[2] + scr[3];
}

__device__ __forceinline__ void blockSum4(float v[4], float (*scr4)[4]) {
    const int tid = threadIdx.x;
    const int wid = tid >> 6, lane = tid & 63;
#pragma unroll
    for (int off = 32; off; off >>= 1) {
#pragma unroll
        for (int q = 0; q < 4; ++q) v[q] += __shfl_xor(v[q], off, 64);
    }
    __syncthreads();
    if (lane == 0) {
#pragma unroll
        for (int q = 0; q < 4; ++q) scr4[wid][q] = v[q];
    }
    __syncthreads();
#pragma unroll
    for (int q = 0; q < 4; ++q)
        v[q] = scr4[0][q] + scr4[1][q] + scr4[2][q] + scr4[3][q];
}

// split fp32 -> bf16 hi + bf16 lo (truncation; a ~= hi + lo, err ~2^-16 rel)
__device__ __forceinline__ void cvtSplit(float a, short& h, short& l) {
    const unsigned ab = __float_as_uint(a);
    h = (short)(ab >> 16);
    const float hf = __uint_as_float(ab & 0xFFFF0000u);
    l = (short)(__float_as_uint(a - hf) >> 16);
}

// A-pack index: ((sg*12 + st)*64 + kq*16 + m16)*8 + j
__device__ __forceinline__ size_t aIdx(int sg, int st, int kq, int m16, int j) {
    return ((((size_t)sg * ASTEPS + st) << 6) + (kq << 4) + m16) * 8 + j;
}

// Fused setup: fragment-major bf16-split packing + mask detect + prep.
// blocks [0,256): messages -> msgH/msgL packed (b=bid>>6, T=bid&63)
// [256,320): scn -> scnH/scnL packed (4 tiles per block)
// 320: mask detect + counter zero; [321,833): prep (8 rows each).
__global__ __launch_bounds__(256) void setup_kernel(
    const float* __restrict__ messages, const float* __restrict__ scn,
    const float* __restrict__ hidden, const float* __restrict__ gvel,
    const float* __restrict__ ctx, const float* __restrict__ ent,
    const float* __restrict__ W_probe, const float* __restrict__ W_vel,
    const float* __restrict__ W_gate, const float* __restrict__ b_gate,
    short* __restrict__ msgH, short* __restrict__ msgL,
    short* __restrict__ scnH, short* __restrict__ scnL,
    const unsigned int* __restrict__ maskW, int* __restrict__ flag,
    int* __restrict__ qMeta,
    short* __restrict__ wsAh, short* __restrict__ wsAl,
    float* __restrict__ wsProbe,
    int* __restrict__ wsMode, float* __restrict__ wsGw)
{
    const int bid = blockIdx.x;
    const int tid = threadIdx.x;

    if (bid < 256) {   // messages -> packed fragments
        const int b = bid >> 6, T = bid & 63;
        const float* src = messages + (size_t)b * SEQ_ * D_;
        short* dh = msgH + (size_t)b * MSGP_B;
        short* dl = msgL + (size_t)b * MSGP_B;
#pragma unroll
        for (int it = 0; it < 2; ++it) {
            const int g = (it << 8) + tid;         // 0..511
            const int st = g >> 6, kq = (g >> 4) & 3, m16 = g & 15;
            const int t = (T << 4) + m16;
            const int k0 = (st << 5) + (kq << 3);
            const float4 v0 = *(const float4*)(src + (size_t)t * D_ + k0);
            const float4 v1 = *(const float4*)(src + (size_t)t * D_ + k0 + 4);
            short h[8], l[8];
            cvtSplit(v0.x, h[0], l[0]); cvtSplit(v0.y, h[1], l[1]);
            cvtSplit(v0.z, h[2], l[2]); cvtSplit(v0.w, h[3], l[3]);
            cvtSplit(v1.x, h[4], l[4]); cvtSplit(v1.y, h[5], l[5]);
            cvtSplit(v1.z, h[6], l[6]); cvtSplit(v1.w, h[7], l[7]);
            const size_t o = (((size_t)T * 8 + st) << 9) + (size_t)((kq << 4) + m16) * 8;
            *(short4*)(dh + o) = make_short4(h[0], h[1], h[2], h[3]);
            *(short4*)(dh + o + 4) = make_short4(h[4], h[5], h[6], h[7]);
            *(short4*)(dl + o) = make_short4(l[0], l[1], l[2], l[3]);
            *(short4*)(dl + o + 4) = make_short4(l[4], l[5], l[6], l[7]);
        }
        return;
    }

    if (bid < 320) {   // scn -> packed fragments, 4 tiles per block
        const int i = bid - 256;
        const int b = i >> 4;
        const float* src = scn + (size_t)b * SEQ_ * NS_;
        short* dh = scnH + (size_t)b * SCNP_B;
        short* dl = scnL + (size_t)b * SCNP_B;
#pragma unroll
        for (int tt = 0; tt < 4; ++tt) {
            const int T = ((i & 15) << 2) + tt;
            if (tid < 128) {
                const int st = tid >> 6, kq = (tid >> 4) & 3, m16 = tid & 15;
                const int t = (T << 4) + m16;
                const int k0 = (st << 5) + (kq << 3);
                const float4 v0 = *(const float4*)(src + (size_t)t * NS_ + k0);
                const float4 v1 = *(const float4*)(src + (size_t)t * NS_ + k0 + 4);
                short h[8], l[8];
                cvtSplit(v0.x, h[0], l[0]); cvtSplit(v0.y, h[1], l[1]);
                cvtSplit(v0.z, h[2], l[2]); cvtSplit(v0.w, h[3], l[3]);
                cvtSplit(v1.x, h[4], l[4]); cvtSplit(v1.y, h[5], l[5]);
                cvtSplit(v1.z, h[6], l[6]); cvtSplit(v1.w, h[7], l[7]);
                const size_t o = (((size_t)T * 2 + st) << 9) + (size_t)((kq << 4) + m16) * 8;
                *(short4*)(dh + o) = make_short4(h[0], h[1], h[2], h[3]);
                *(short4*)(dh + o + 4) = make_short4(h[4], h[5], h[6], h[7]);
                *(short4*)(dl + o) = make_short4(l[0], l[1], l[2], l[3]);
                *(short4*)(dl + o + 4) = make_short4(l[4], l[5], l[6], l[7]);
            }
        }
        return;
    }

    if (bid == 320) {
        __shared__ int notI, notF;
        if (tid == 0) { notI = 0; notF = 0; qMeta[0] = 0; qMeta[1] = 0; }
        __syncthreads();
        int ni = 0, nf = 0;
        for (int i = tid; i < 1024; i += 256) {
            const unsigned int w = maskW[i];
            if (w != 0u && w != 1u) ni = 1;
            if (w != 0u && w != 0x3f800000u) nf = 1;
        }
        if (ni) atomicOr(&notI, 1);
        if (nf) atomicOr(&notF, 1);
        __syncthreads();
        if (tid == 0) *flag = (!notI) ? 0 : ((!notF) ? 2 : 1);
        return;
    }

    // ---- prep: 8 rows per block; A written in fragment-major pack ----
    __shared__ float scr4[4][4];
    const int rowBase = (bid - 321) << 3;
    const int wid = tid >> 6, lane = tid & 63;
    const float* h0 = hidden + (size_t)rowBase * D_;

    float vh[8] = {};
    for (int e = 0; e < NS_; e += 4) {
        const float4 wv4 = *(const float4*)(W_vel + (size_t)tid * NS_ + e);  // thread-own row
#pragma unroll
        for (int r = 0; r < 8; ++r) {
            const float4 g4 = *(const float4*)(gvel + (size_t)(rowBase + r) * NS_ + e); // uniform
            vh[r] = fmaf(g4.x, wv4.x, fmaf(g4.y, wv4.y, fmaf(g4.z, wv4.z, fmaf(g4.w, wv4.w, vh[r]))));
        }
    }
    float pr[8] = {};
    for (int e = 0; e < D_; e += 4) {
        const float4 wp4 = *(const float4*)(W_probe + (size_t)tid * D_ + e);  // thread-own row
#pragma unroll
        for (int r = 0; r < 8; ++r) {
            const float4 h4 = *(const float4*)(h0 + (size_t)r * D_ + e);      // uniform
            pr[r] = fmaf(h4.x, wp4.x, fmaf(h4.y, wp4.y, fmaf(h4.z, wp4.z, fmaf(h4.w, wp4.w, pr[r]))));
        }
    }

    // per-wave: wave w handles rows 2w, 2w+1 (endpoint e', s', argmax, gate)
#pragma unroll
    for (int rr = 0; rr < 2; ++rr) {
        const int r = (wid << 1) + rr, row = rowBase + r;
        const int sg = row >> 4, m16 = row & 15;
        const float sv = scn[(size_t)row * NS_ + lane];
        const float gv = gvel[(size_t)row * NS_ + lane];
        const float Hn = ent[row] / 10.373491191781864f;   // log(32000)+1e-8
        const float e = sv + 0.4f * gv;
        const float ss = waveSum(e * e);
        const int stE = lane >> 5, kqE = (lane & 31) >> 3, jE = lane & 7;
        short hh, ll;
        cvtSplit((e / fmaxf(sqrtf(ss), 1e-12f)) * 5.0f * Hn, hh, ll);
        wsAh[aIdx(sg, stE, kqE, m16, jE)] = hh;
        wsAl[aIdx(sg, stE, kqE, m16, jE)] = ll;
        cvtSplit(5.0f * sv, hh, ll);
        wsAh[aIdx(sg, 2 + stE, kqE, m16, jE)] = hh;
        wsAl[aIdx(sg, 2 + stE, kqE, m16, jE)] = ll;
        float v = sv; int idx = lane;
#pragma unroll
        for (int off = 1; off < 64; off <<= 1) {
            const float ov = __shfl_xor(v, off, 64);
            const int   oi = __shfl_xor(idx, off, 64);
            if (ov > v || (ov == v && oi < idx)) { v = ov; idx = oi; }
        }
        float gd = 0.f;
#pragma unroll
        for (int j = 0; j < 4; ++j) {
            const int d = lane + (j << 6);
            gd = fmaf(h0[(size_t)r * D_ + d], W_gate[d], gd);
        }
        gd = waveSum(gd);
        if (lane == 0) {
            wsMode[row] = idx;
            const float raw = 1.f / (1.f + expf(-(gd + b_gate[0])));
            wsGw[row] = raw * ctx[row];
        }
    }

    // block-wide norms; h' written packed
    const int stH = 4 + (tid >> 5), kqH = (tid & 31) >> 3, jH = tid & 7;
#pragma unroll
    for (int g = 0; g < 2; ++g) {
        float ha4[4], va[4], vp[4];
#pragma unroll
        for (int q = 0; q < 4; ++q) {
            const int r = (g << 2) + q;
            ha4[q] = h0[(size_t)r * D_ + tid] + 0.3f * vh[r];
            va[q] = ha4[q] * ha4[q];
            vp[q] = pr[(g << 2) + q] * pr[(g << 2) + q];
        }
        blockSum4(va, scr4);
        blockSum4(vp, scr4);
#pragma unroll
        for (int q = 0; q < 4; ++q) {
            const int r = (g << 2) + q;
            const int row = rowBase + r;
            const int sg = row >> 4, m16 = row & 15;
            short hh, ll;
            cvtSplit((ha4[q] / fmaxf(sqrtf(va[q]), 1e-12f)) * 2.5f, hh, ll);
            wsAh[aIdx(sg, stH, kqH, m16, jH)] = hh;
            wsAl[aIdx(sg, stH, kqH, m16, jH)] = ll;
            wsProbe[(size_t)row * D_ + tid] = pr[r] / fmaxf(sqrtf(vp[q]), 1e-12f);
        }
    }
}

// Kernel A: all-pairs sims via split-bf16 MFMA, fragment-packed operands.
// 512 blocks = b(4) x rowgroup32(32) x colquarter(4); 8 waves x 2 A-tiles x
// 2 col-tiles.  A fragments (48 KB, shared by all 8 waves) staged in LDS.
__global__ __launch_bounds__(512) void sims_kernel(
    const short* __restrict__ msgH, const short* __restrict__ msgL,   // packed
    const short* __restrict__ scnH, const short* __restrict__ scnL,   // packed
    const short* __restrict__ wsAh, const short* __restrict__ wsAl,   // packed
    const int* __restrict__ wsMode,
    const void* __restrict__ maskP,
    const int* __restrict__ maskFlag,
    float* __restrict__ zgO,            // [4096][1024]
    float* __restrict__ zlO)            // [4096][1024]
{
    __shared__ short shAh[2][ASTEPS][512];   // 24 KB: [tile][step][lane*8]
    __shared__ short shAl[2][ASTEPS][512];   // 24 KB
    const int bid = blockIdx.x;          // 512 blocks
    const int b = bid >> 7;
    const int rem = bid & 127;
    const int rg = rem >> 2;             // 32-row group (0..31)
    const int qt = rem & 3;              // column quarter (256 cols)
    const int sBase = rg << 5;           // 32 rows
    const int rowBase = (b << 10) + sBase;
    const int tid = threadIdx.x;
    const int w = tid >> 6, l = tid & 63;
    const int m16 = l & 15, kq = l >> 4;
    const int l8 = l << 3;

    const int sgA = (b << 6) + (rg << 1);       // first 16-row group in A pack
    {   // cooperative stage of both A tiles (hi+lo), 16B coalesced
        const short* srcH = wsAh + (size_t)sgA * (ASTEPS * 512);
        const short* srcL = wsAl + (size_t)sgA * (ASTEPS * 512);
        short* dH = &shAh[0][0][0];
        short* dL = &shAl[0][0][0];
#pragma unroll
        for (int i = 0; i < 3; ++i) {
            const int c = (i << 9) + tid;        // 0..1535 chunks of 8 shorts
            *(bf16x8*)(dH + c * 8) = *(const bf16x8*)(srcH + c * 8);
            *(bf16x8*)(dL + c * 8) = *(const bf16x8*)(srcL + c * 8);
        }
    }
    __syncthreads();

    f32x4 accG[2][2], accL8[2][2];
#pragma unroll
    for (int mA = 0; mA < 2; ++mA)
#pragma unroll
        for (int ct = 0; ct < 2; ++ct) {
            accG[mA][ct] = (f32x4){0.f, 0.f, 0.f, 0.f};
            accL8[mA][ct] = (f32x4){0.f, 0.f, 0.f, 0.f};
        }

    // ---- scn k-steps (2): e' -> accG, s' -> accL, shared B loads ----
#pragma unroll
    for (int st = 0; st < 2; ++st) {
        const bf16x8 aeh0 = *(const bf16x8*)(&shAh[0][st][l8]);
        const bf16x8 ael0 = *(const bf16x8*)(&shAl[0][st][l8]);
        const bf16x8 ash0 = *(const bf16x8*)(&shAh[0][2 + st][l8]);
        const bf16x8 asl0 = *(const bf16x8*)(&shAl[0][2 + st][l8]);
        const bf16x8 aeh1 = *(const bf16x8*)(&shAh[1][st][l8]);
        const bf16x8 ael1 = *(const bf16x8*)(&shAl[1][st][l8]);
        const bf16x8 ash1 = *(const bf16x8*)(&shAh[1][2 + st][l8]);
        const bf16x8 asl1 = *(const bf16x8*)(&shAl[1][2 + st][l8]);
#pragma unroll
        for (int ct = 0; ct < 2; ++ct) {
            const int mtile = (qt << 4) + (w << 1) + ct;
            const size_t bo = (size_t)b * SCNP_B + (((size_t)mtile * 2 + st) << 9) + l8;
            const bf16x8 bh = *(const bf16x8*)(scnH + bo);
            const bf16x8 bl = *(const bf16x8*)(scnL + bo);
            accG[0][ct] = __builtin_amdgcn_mfma_f32_16x16x32_bf16(aeh0, bh, accG[0][ct], 0, 0, 0);
            accG[0][ct] = __builtin_amdgcn_mfma_f32_16x16x32_bf16(aeh0, bl, accG[0][ct], 0, 0, 0);
            accG[0][ct] = __builtin_amdgcn_mfma_f32_16x16x32_bf16(ael0, bh, accG[0][ct], 0, 0, 0);
            accL8[0][ct] = __builtin_amdgcn_mfma_f32_16x16x32_bf16(ash0, bh, accL8[0][ct], 0, 0, 0);
            accL8[0][ct] = __builtin_amdgcn_mfma_f32_16x16x32_bf16(ash0, bl, accL8[0][ct], 0, 0, 0);
            accL8[0][ct] = __builtin_amdgcn_mfma_f32_16x16x32_bf16(asl0, bh, accL8[0][ct], 0, 0, 0);
            accG[1][ct] = __builtin_amdgcn_mfma_f32_16x16x32_bf16(aeh1, bh, accG[1][ct], 0, 0, 0);
            accG[1][ct] = __builtin_amdgcn_mfma_f32_16x16x32_bf16(aeh1, bl, accG[1][ct], 0, 0, 0);
            accG[1][ct] = __builtin_amdgcn_mfma_f32_16x16x32_bf16(ael1, bh, accG[1][ct], 0, 0, 0);
            accL8[1][ct] = __builtin_amdgcn_mfma_f32_16x16x32_bf16(ash1, bh, accL8[1][ct], 0, 0, 0);
            accL8[1][ct] = __builtin_amdgcn_mfma_f32_16x16x32_bf16(ash1, bl, accL8[1][ct], 0, 0, 0);
            accL8[1][ct] = __builtin_amdgcn_mfma_f32_16x16x32_bf16(asl1, bh, accL8[1][ct], 0, 0, 0);
        }
    }
    // ---- msg k-steps (8): h' -> accG ----
#pragma unroll
    for (int st = 0; st < 8; ++st) {
        const bf16x8 ah0 = *(const bf16x8*)(&shAh[0][4 + st][l8]);
        const bf16x8 al0 = *(const bf16x8*)(&shAl[0][4 + st][l8]);
        const bf16x8 ah1 = *(const bf16x8*)(&shAh[1][4 + st][l8]);
        const bf16x8 al1 = *(const bf16x8*)(&shAl[1][4 + st][l8]);
#pragma unroll
        for (int ct = 0; ct < 2; ++ct) {
            const int mtile = (qt << 4) + (w << 1) + ct;
            const size_t bo = (size_t)b * MSGP_B + (((size_t)mtile * 8 + st) << 9) + l8;
            const bf16x8 bh = *(const bf16x8*)(msgH + bo);
            const bf16x8 bl = *(const bf16x8*)(msgL + bo);
            accG[0][ct] = __builtin_amdgcn_mfma_f32_16x16x32_bf16(ah0, bh, accG[0][ct], 0, 0, 0);
            accG[0][ct] = __builtin_amdgcn_mfma_f32_16x16x32_bf16(ah0, bl, accG[0][ct], 0, 0, 0);
            accG[0][ct] = __builtin_amdgcn_mfma_f32_16x16x32_bf16(al0, bh, accG[0][ct], 0, 0, 0);
            accG[1][ct] = __builtin_amdgcn_mfma_f32_16x16x32_bf16(ah1, bh, accG[1][ct], 0, 0, 0);
            accG[1][ct] = __builtin_amdgcn_mfma_f32_16x16x32_bf16(ah1, bl, accG[1][ct], 0, 0, 0);
            accG[1][ct] = __builtin_amdgcn_mfma_f32_16x16x32_bf16(al1, bh, accG[1][ct], 0, 0, 0);
        }
    }

    // ---- tail: mask + mode; write zg + raw zl ----
    const int tBase = (qt << 8) + (w << 5);
    const int mf = *maskFlag;
#pragma unroll
    for (int mA = 0; mA < 2; ++mA) {
        const int4 mS4 = *(const int4*)(wsMode + rowBase + (mA << 4) + (kq << 2));
        const int mSq[4] = {mS4.x, mS4.y, mS4.z, mS4.w};
#pragma unroll
        for (int ct = 0; ct < 2; ++ct) {
            const int t = tBase + (ct << 4) + m16;
            const int mdt = wsMode[(b << 10) + t];
#pragma unroll
            for (int q = 0; q < 4; ++q) {
                const int r = (mA << 4) + (kq << 2) + q;
                const int s_r = sBase + r;
                const size_t mb = (size_t)s_r * SEQ_ + t;
                int blk;
                if (mf == 1)      blk = ((const unsigned char*)maskP)[mb] != 0;
                else if (mf == 2) blk = ((const float*)maskP)[mb] != 0.f;
                else              blk = ((const int*)maskP)[mb] != 0;
                if (s_r == t) blk = 1;
                zgO[(size_t)(rowBase + r) * SEQ_ + t] = blk ? NEG_ : accG[mA][ct][q];
                const int sm = (!blk) && (mdt == mSq[q]);
                zlO[(size_t)(rowBase + r) * SEQ_ + t] =
                    blk ? BLKNEG_ : (sm ? accL8[mA][ct][q] : 0.0f);
            }
        }
    }
}

// Kernel B: 4 waves per block, wave owns one row (mirror-balanced).
// hasNb derived in-row from raw zl; JOINT tau iteration for geo+local.
// Sparse combined gather; dense rows deferred to cleanup via queue.
__global__ __launch_bounds__(256) void route4_kernel(
    const float* __restrict__ messages,
    const float* __restrict__ scn,
    const int* __restrict__ x_ids,
    const int* __restrict__ static_nb,
    const float* __restrict__ W_e1,
    const float* __restrict__ b_e1,
    const float* __restrict__ W_e2,
    const float* __restrict__ b_e2,
    const float* __restrict__ wsProbe,
    const float* __restrict__ wsGw,
    const float* __restrict__ zgA,
    const float* __restrict__ zlA,
    float* __restrict__ wq,          // [MAXQ][1024] dense weights
    int* __restrict__ qRows,
    int* __restrict__ qMeta,         // [0]=tail, [1]=consume
    float* __restrict__ out)
{
    __shared__ uint2 lst[4][256];
    __shared__ float ewLds[4][8];
    __shared__ int   mlist[4][64];

    const int jb = blockIdx.x;               // 0..1023
    const int tid = threadIdx.x;
    const int wid = tid >> 6, lane = tid & 63;
    const int base = jb << 1;
    const int row = (wid == 0) ? base
                  : (wid == 1) ? base + 1
                  : (wid == 2) ? 4094 - base
                               : 4095 - base;
    const int b = row >> 10, s_r = row & 1023;
    const float* msgB = messages + (size_t)b * SEQ_ * D_;
    const float* scnB = scn + (size_t)b * SEQ_ * NS_;
    const unsigned long long ltmask = (1ull << lane) - 1ull;
    const int d4 = lane << 2;

    float zrG[16], zrL[16];
    {
        const float4* zgp = (const float4*)(zgA + (size_t)row * SEQ_ + (lane << 4));
        const float4* zlp = (const float4*)(zlA + (size_t)row * SEQ_ + (lane << 4));
#pragma unroll
        for (int q = 0; q < 4; ++q) {
            const float4 g4 = zgp[q];
            zrG[q * 4 + 0] = g4.x; zrG[q * 4 + 1] = g4.y;
            zrG[q * 4 + 2] = g4.z; zrG[q * 4 + 3] = g4.w;
            const float4 l4 = zlp[q];
            zrL[q * 4 + 0] = l4.x; zrL[q * 4 + 1] = l4.y;
            zrL[q * 4 + 2] = l4.z; zrL[q * 4 + 3] = l4.w;
        }
    }

    // ----- static neighbor-vocab scan: ONE ballot per 64-block (kmask) -----
    const int q = x_ids[row];
    int nb[KNB_];
#pragma unroll
    for (int k = 0; k < KNB_; ++k) nb[k] = static_nb[(size_t)q * KNB_ + k];
    const float ss_l = scnB[(size_t)s_r * NS_ + lane];
    float simk[KNB_] = {};
    unsigned matchedMask = 0;
    int mcW = 0;
    const int* xb = x_ids + (b << 10);
    for (int pb = 0; pb <= s_r; pb += 64) {
        const int p = pb + lane;
        const int id = (p <= s_r) ? xb[p] : -2147483647;
        unsigned kmask = 0;
#pragma unroll
        for (int k = 0; k < KNB_; ++k) kmask |= (id == nb[k]) ? (1u << k) : 0u;
        unsigned long long mb = __ballot(kmask != 0u);
        while (mb) {
            const int src = __ffsll(mb) - 1; mb &= mb - 1;
            const unsigned kms = (unsigned)__shfl((int)kmask, src, 64);
            const int pp = pb + src;
            float pv = scnB[(size_t)pp * NS_ + lane] * ss_l;
            pv = waveSum(pv);
            matchedMask |= kms;
#pragma unroll
            for (int k = 0; k < KNB_; ++k) {
                if ((kms >> k) & 1u) {
                    simk[k] += pv;
                    if (mcW < 64) { if (lane == 0) mlist[wid][mcW] = (pp << 3) | k; ++mcW; }
                }
            }
        }
    }
    const int kk = lane >> 3, jjn = lane & 7;
    float sv = simk[0];
#pragma unroll
    for (int k = 1; k < KNB_; ++k) sv = (kk == k) ? simk[k] : sv;
    const float xx = sv * W_e1[jjn] + b_e1[jjn];
    float eo = 0.5f * xx * (1.f + erff(xx * 0.70710678118654752f)) * W_e2[jjn];
    eo += __shfl_xor(eo, 1, 64); eo += __shfl_xor(eo, 2, 64); eo += __shfl_xor(eo, 4, 64);
    eo += b_e2[0];
    float m2 = eo;
    m2 = fmaxf(m2, __shfl_xor(m2, 8, 64));
    m2 = fmaxf(m2, __shfl_xor(m2, 16, 64));
    m2 = fmaxf(m2, __shfl_xor(m2, 32, 64));
    const float exv = expf(eo - m2);
    float smv = exv;
    smv += __shfl_xor(smv, 8, 64); smv += __shfl_xor(smv, 16, 64); smv += __shfl_xor(smv, 32, 64);
    if ((lane & 7) == 0) ewLds[wid][kk] = exv / smv;

    const float cov = (float)__popc(matchedMask) * 0.125f;
    const float gw = wsGw[row];
    const float coefG = gw;
    const float coefL = (1.f - gw) * (1.f - cov);
    const float coefS = (1.f - gw) * cov;

    // ----- local hasNb derived from raw zl -----
    int fl = 0;
#pragma unroll
    for (int j = 0; j < 16; ++j) fl |= (zrL[j] != 0.0f && zrL[j] > -40000.f);
    const int hasNb = __any(fl);
    if (!hasNb) {
#pragma unroll
        for (int j = 0; j < 16; ++j) {
            const int t = (lane << 4) + j;
            zrL[j] = (zrL[j] <= -40000.f) ? BLKNEG_ : -0.05f * fabsf((float)(s_r - t));
        }
    }

    // ----- JOINT sparsemax tau (geo + local lockstep, batched butterflies) -----
    float mxG = zrG[0], mxL = zrL[0];
#pragma unroll
    for (int j = 1; j < 16; ++j) { mxG = fmaxf(mxG, zrG[j]); mxL = fmaxf(mxL, zrL[j]); }
#pragma unroll
    for (int off = 32; off; off >>= 1) {
        mxG = fmaxf(mxG, __shfl_xor(mxG, off, 64));
        mxL = fmaxf(mxL, __shfl_xor(mxL, off, 64));
    }
    float tauG = mxG - 1.f, tauL = mxL - 1.f;
    for (int it = 0; it < 32; ++it) {
        float sG = 0.f, cG = 0.f, sL = 0.f, cL = 0.f;
#pragma unroll
        for (int j = 0; j < 16; ++j) {
            if (zrG[j] > tauG) { sG += zrG[j]; cG += 1.f; }
            if (zrL[j] > tauL) { sL += zrL[j]; cL += 1.f; }
        }
#pragma unroll
        for (int off = 32; off; off >>= 1) {
            sG += __shfl_xor(sG, off, 64); cG += __shfl_xor(cG, off, 64);
            sL += __shfl_xor(sL, off, 64); cL += __shfl_xor(cL, off, 64);
        }
        const float nG = (sG - 1.f) / fmaxf(cG, 1.f);
        const float nL = (sL - 1.f) / fmaxf(cL, 1.f);
        if (nG == tauG && nL == tauL) break;
        tauG = nG; tauL = nL;
    }

    int supG = 0, supL = 0;
#pragma unroll
    for (int j = 0; j < 16; ++j) {
        supG += __popcll(__ballot(zrG[j] > tauG));
        supL += __popcll(__ballot(zrL[j] > tauL));
    }
    const bool gDense = supG > 96;
    const bool lDense = supL > 96;

    int cnt = 0;
    if (!gDense) {
#pragma unroll
        for (int j = 0; j < 16; ++j) {
            const float wv = zrG[j] - tauG;
            const bool take = wv > 0.f;
            const unsigned long long m = __ballot(take);
            if (take) {
                const int pos = cnt + __popcll(m & ltmask);
                lst[wid][pos] = make_uint2((unsigned)((lane << 4) + j),
                                           __float_as_uint(coefG * wv));
            }
            cnt += __popcll(m);
        }
    }
    if (!lDense) {
#pragma unroll
        for (int j = 0; j < 16; ++j) {
            const float wv = zrL[j] - tauL;
            const bool take = wv > 0.f;
            const unsigned long long m = __ballot(take);
            if (take) {
                const int pos = cnt + __popcll(m & ltmask);
                lst[wid][pos] = make_uint2((unsigned)((lane << 4) + j),
                                           __float_as_uint(coefL * wv));
            }
            cnt += __popcll(m);
        }
    }
    const int nm = (mcW < 64) ? mcW : 64;
    for (int i = lane; i < nm; i += 64) {
        const int ee = mlist[wid][i];
        lst[wid][cnt + i] = make_uint2((unsigned)(ee >> 3),
                                       __float_as_uint(coefS * ewLds[wid][ee & 7]));
    }
    cnt += nm;

    float ox = 0.f, oy = 0.f, oz2 = 0.f, ow = 0.f;
    int i = 0;
    for (; i + 4 <= cnt; i += 4) {
        const uint2 e0 = lst[wid][i + 0];
        const uint2 e1 = lst[wid][i + 1];
        const uint2 e2 = lst[wid][i + 2];
        const uint2 e3 = lst[wid][i + 3];
        const float4 m0 = *(const float4*)(msgB + (size_t)e0.x * D_ + d4);
        const float4 m1 = *(const float4*)(msgB + (size_t)e1.x * D_ + d4);
        const float4 m2b = *(const float4*)(msgB + (size_t)e2.x * D_ + d4);
        const float4 m3 = *(const float4*)(msgB + (size_t)e3.x * D_ + d4);
        const float w0 = __uint_as_float(e0.y), w1 = __uint_as_float(e1.y);
        const float w2 = __uint_as_float(e2.y), w3 = __uint_as_float(e3.y);
        ox = fmaf(w0, m0.x, fmaf(w1, m1.x, fmaf(w2, m2b.x, fmaf(w3, m3.x, ox))));
        oy = fmaf(w0, m0.y, fmaf(w1, m1.y, fmaf(w2, m2b.y, fmaf(w3, m3.y, oy))));
        oz2 = fmaf(w0, m0.z, fmaf(w1, m1.z, fmaf(w2, m2b.z, fmaf(w3, m3.z, oz2))));
        ow = fmaf(w0, m0.w, fmaf(w1, m1.w, fmaf(w2, m2b.w, fmaf(w3, m3.w, ow))));
    }
    for (; i < cnt; ++i) {
        const uint2 e0 = lst[wid][i];
        const float w0 = __uint_as_float(e0.y);
        const float4 m0 = *(const float4*)(msgB + (size_t)e0.x * D_ + d4);
        ox = fmaf(w0, m0.x, ox); oy = fmaf(w0, m0.y, oy);
        oz2 = fmaf(w0, m0.z, oz2); ow = fmaf(w0, m0.w, ow);
    }

    int slot = -1;
    if (gDense || lDense) {
        int s0 = 0;
        if (lane == 0) s0 = atomicAdd(&qMeta[0], 1);
        slot = __shfl(s0, 0, 64);
    }
    if (slot >= 0 && slot < MAXQ_) {
#pragma unroll
        for (int qd = 0; qd < 4; ++qd) {
            float4 w4;
            float* wv4 = &w4.x;
#pragma unroll
            for (int u = 0; u < 4; ++u) {
                const int j = qd * 4 + u;
                float w = 0.f;
                if (gDense) w += coefG * fmaxf(zrG[j] - tauG, 0.f);
                if (lDense) w += coefL * fmaxf(zrL[j] - tauL, 0.f);
                wv4[u] = w;
            }
            *(float4*)(wq + (size_t)slot * SEQ_ + (lane << 4) + qd * 4) = w4;
        }
        if (lane == 0) qRows[slot] = row;
        *(float4*)(out + (size_t)row * D_ + d4) = make_float4(ox, oy, oz2, ow);
        return;
    }
    if (slot >= MAXQ_) {
#pragma unroll
        for (int j = 0; j < 16; ++j) {
            float wv = 0.f;
            if (gDense) wv += coefG * fmaxf(zrG[j] - tauG, 0.f);
            if (lDense) wv += coefL * fmaxf(zrL[j] - tauL, 0.f);
            unsigned long long m = __ballot(wv > 0.f);
            while (m) {
                const int s0 = __ffsll(m) - 1; m &= m - 1;
                const float w0 = __shfl(wv, s0, 64);
                const float4 m4 = *(const float4*)(msgB + (size_t)((s0 << 4) + j) * D_ + d4);
                ox = fmaf(w0, m4.x, ox); oy = fmaf(w0, m4.y, oy);
                oz2 = fmaf(w0, m4.z, oz2); ow = fmaf(w0, m4.w, ow);
            }
        }
    }

    float ssq = ox * ox + oy * oy + oz2 * oz2 + ow * ow;
    ssq = waveSum(ssq);
    const float nrm = fmaxf(sqrtf(ssq), 1e-12f);
    const float4 pr = *(const float4*)(wsProbe + (size_t)row * D_ + d4);
    float dp = (ox * pr.x + oy * pr.y + oz2 * pr.z + ow * pr.w) / nrm;
    dp = waveSum(dp);
    const float rel = 1.f / (1.f + expf(-dp));
    *(float4*)(out + (size_t)row * D_ + d4) =
        make_float4(ox * rel, oy * rel, oz2 * rel, ow * rel);
}

// Kernel C: drain dense-row queue.
__global__ __launch_bounds__(256) void cleanup_kernel(
    const float* __restrict__ messages,
    const float* __restrict__ wsProbe,
    const float* __restrict__ wq,
    const int* __restrict__ qRows,
    int* __restrict__ qMeta,
    float* __restrict__ out)
{
    __shared__ float wsh[SEQ_];
    __shared__ float scr[4];
    __shared__ int idxSh;
    const int tid = threadIdx.x;
    const int nq = (qMeta[0] < MAXQ_) ? qMeta[0] : MAXQ_;
    for (;;) {
        __syncthreads();
        if (tid == 0) idxSh = atomicAdd(&qMeta[1], 1);
        __syncthreads();
        const int idx = idxSh;
        if (idx >= nq) break;
        const int row = qRows[idx];
        const int b = row >> 10;
        const float* msgB = messages + (size_t)b * SEQ_ * D_;
        for (int i = tid; i < SEQ_; i += 256)
            wsh[i] = wq[(size_t)idx * SEQ_ + i];
        __syncthreads();
        float acc = out[(size_t)row * D_ + tid];
        for (int t = 0; t < SEQ_; t += 4) {
            acc = fmaf(wsh[t + 0], msgB[(size_t)(t + 0) * D_ + tid],
                  fmaf(wsh[t + 1], msgB[(size_t)(t + 1) * D_ + tid],
                  fmaf(wsh[t + 2], msgB[(size_t)(t + 2) * D_ + tid],
                  fmaf(wsh[t + 3], msgB[(size_t)(t + 3) * D_ + tid], acc))));
        }
        const float ssq = blockSum(acc * acc, scr);
        const float nrm = fmaxf(sqrtf(ssq), 1e-12f);
        const float dp = blockSum((acc / nrm) * wsProbe[(size_t)row * D_ + tid], scr);
        const float rel = 1.f / (1.f + expf(-dp));
        out[(size_t)row * D_ + tid] = acc * rel;
    }
}

extern "C" void kernel_launch(void* const* d_in, const int* in_sizes, int n_in,
                              void* d_out, int out_size, void* d_ws, size_t ws_size,
                              hipStream_t stream) {
    const float* messages  = (const float*)d_in[0];
    const float* hidden    = (const float*)d_in[1];
    const int*   x_ids     = (const int*)d_in[2];
    const float* scn       = (const float*)d_in[3];
    const void*  mask      = d_in[4];
    const int*   static_nb = (const int*)d_in[5];
    const float* gvel      = (const float*)d_in[6];
    const float* ctx       = (const float*)d_in[7];
    const float* ent       = (const float*)d_in[8];
    const float* W_vel     = (const float*)d_in[9];
    const float* W_e1      = (const float*)d_in[10];
    const float* b_e1      = (const float*)d_in[11];
    const float* W_e2      = (const float*)d_in[12];
    const float* b_e2      = (const float*)d_in[13];
    const float* W_probe   = (const float*)d_in[14];
    const float* W_gate    = (const float*)d_in[15];
    const float* b_gate    = (const float*)d_in[16];
    float* out = (float*)d_out;
    (void)in_sizes; (void)n_in; (void)out_size; (void)ws_size;

    char* ws = (char*)d_ws;
    size_t o = 0;
    int* flag      = (int*)(ws + o);   o += 256;
    short* wsAh    = (short*)(ws + o); o += (size_t)B_ * SEQ_ * 384 * 2;   // 3.1 MB packed
    short* wsAl    = (short*)(ws + o); o += (size_t)B_ * SEQ_ * 384 * 2;
    float* wsProbe = (float*)(ws + o); o += (size_t)B_ * SEQ_ * D_ * 4;
    int* wsMode    = (int*)(ws + o);   o += (size_t)B_ * SEQ_ * 4;
    float* wsGw    = (float*)(ws + o); o += (size_t)B_ * SEQ_ * 4;
    short* msgH    = (short*)(ws + o); o += (size_t)B_ * MSGP_B * 2;       // 2 MB packed
    short* msgL    = (short*)(ws + o); o += (size_t)B_ * MSGP_B * 2;
    short* scnH    = (short*)(ws + o); o += (size_t)B_ * SCNP_B * 2;
    short* scnL    = (short*)(ws + o); o += (size_t)B_ * SCNP_B * 2;
    float* zgW     = (float*)(ws + o); o += (size_t)B_ * SEQ_ * SEQ_ * 4;
    float* zlW     = (float*)(ws + o); o += (size_t)B_ * SEQ_ * SEQ_ * 4;
    int* qMeta     = (int*)(ws + o);   o += 256;
    int* qRows     = (int*)(ws + o);   o += (size_t)MAXQ_ * 4;
    // dense-weight buffer overlays msgH+msgL (dead after sims): 4 MB
    float* wq      = (float*)msgH;

    setup_kernel<<<dim3(833), dim3(256), 0, stream>>>(
        messages, scn, hidden, gvel, ctx, ent, W_probe, W_vel, W_gate, b_gate,
        msgH, msgL, scnH, scnL, (const unsigned int*)mask, flag, qMeta,
        wsAh, wsAl, wsProbe, wsMode, wsGw);
    sims_kernel<<<dim3(512), dim3(512), 0, stream>>>(
        msgH, msgL, scnH, scnL, wsAh, wsAl, wsMode, mask, flag, zgW, zlW);
    route4_kernel<<<dim3(B_ * SEQ_ / 4), dim3(256), 0, stream>>>(
        messages, scn, x_ids, static_nb, W_e1, b_e1, W_e2, b_e2,
        wsProbe, wsGw, zgW, zlW, wq, qRows, qMeta, out);
    cleanup_kernel<<<dim3(64), dim3(256), 0, stream>>>(
        messages, wsProbe, wq, qRows, qMeta, out);
}